// Round 1
// baseline (119.801 us; speedup 1.0000x reference)
//
#include <hip/hip_runtime.h>
#include <hip/hip_bf16.h>

typedef float f32x4  __attribute__((ext_vector_type(4)));
typedef float f32x16 __attribute__((ext_vector_type(16)));
typedef short s16x8  __attribute__((ext_vector_type(8)));

#define NB 4
#define NC 128
#define NNPOS 4096
#define KSP 6          // R10: 8 -> 6. grid 768 = exactly 3 blocks/CU (no 4th-block
                       // tail) and Ow partial traffic 33.5 -> 25.2 MB.
#define LOG2E 1.44269504088896f

__device__ __forceinline__ short bf16s(float x) {
    __hip_bfloat16 h = __float2bfloat16(x);
    return *reinterpret_cast<short*>(&h);
}
__device__ __forceinline__ int packbf2(float lo, float hi) {
    __hip_bfloat162 t = __float22bfloat162_rn(float2{lo, hi});
    return *reinterpret_cast<int*>(&t);
}
__device__ __forceinline__ float bf2f(unsigned short u) {
    unsigned int v = ((unsigned int)u) << 16;
    return *reinterpret_cast<float*>(&v);
}
__device__ __forceinline__ float exp2fast(float x) {
    return __builtin_amdgcn_exp2f(x);   // native v_exp_f32 (base 2)
}

// ------------------------------------------------------------------
// Kernel 1: QKV projection via bf16 MFMA 16x16x32.
// R10: vt written through an LDS staging tile -> 16B coalesced global
// stores (was ~2M scattered 2B stores at 32B stride). qb/kb packed short4.
// qb/kb: [b][n][16] bf16 (q pre-scaled by log2e so attn uses exp2).
// vt: PV-B-frag tile order [b][key/16][c/32][c%32][slot],
//     slot = swap-bits-2,3 of (key%16)  -> score C/D regs == PV A-frag
//     order in attn (no cross-lane ops).
// ------------------------------------------------------------------
__global__ __launch_bounds__(256) void qkv_kernel(
    const float* __restrict__ x,
    const float* __restrict__ wq, const float* __restrict__ bq,
    const float* __restrict__ wk, const float* __restrict__ bk,
    const float* __restrict__ wv, const float* __restrict__ bv,
    short* __restrict__ qb, short* __restrict__ kb, short* __restrict__ vt)
{
    const int n0  = blockIdx.x * 32;
    const int b   = blockIdx.y;
    const int tid = threadIdx.x;
    const int w = tid >> 6, lane = tid & 63, quad = lane >> 4, nn = lane & 15;

    __shared__ __align__(16) short xsT[32 * 136];
    __shared__ __align__(16) short vstage[4096];   // 2 kg x 4 ct x 32 c x 16 slot

    #pragma unroll
    for (int p = 0; p < 4; ++p) {
        int idx = tid + p * 256;
        int cc = idx >> 3, n4 = (idx & 7) * 4;
        f32x4 xv = *(const f32x4*)&x[((size_t)(b * NC + cc)) * NNPOS + n0 + n4];
        #pragma unroll
        for (int j = 0; j < 4; ++j)
            xsT[(n4 + j) * 136 + cc] = bf16s(xv[j]);
    }

    s16x8 af[3][4];
    bool  live[3];
    f32x4 biasv[3];
    #pragma unroll
    for (int t = 0; t < 3; ++t) {
        int rid = 3 * w + t;
        int R   = rid * 16;
        const float* wsrc = nullptr; const float* bsrc = nullptr; int row0 = 0;
        float scale = 1.0f;
        if (rid < 8)        { wsrc = wv; bsrc = bv; row0 = R; }
        else if (rid == 8)  { wsrc = wq; bsrc = bq; row0 = 0; scale = LOG2E; }
        else if (rid == 10) { wsrc = wk; bsrc = bk; row0 = 0; }
        live[t] = (wsrc != nullptr);
        #pragma unroll
        for (int r = 0; r < 4; ++r)
            biasv[t][r] = live[t] ? scale * bsrc[row0 + quad * 4 + r] : 0.0f;
        if (live[t]) {
            #pragma unroll
            for (int ks = 0; ks < 4; ++ks) {
                const float* src = wsrc + (size_t)(row0 + nn) * NC + ks * 32 + quad * 8;
                f32x4 wa = *(const f32x4*)src;
                f32x4 wb = *(const f32x4*)(src + 4);
                s16x8 f;
                #pragma unroll
                for (int j = 0; j < 4; ++j) {
                    f[j]     = bf16s(scale * wa[j]);
                    f[j + 4] = bf16s(scale * wb[j]);
                }
                af[t][ks] = f;
            }
        }
    }
    __syncthreads();

    f32x4 acc[3][2];
    #pragma unroll
    for (int t = 0; t < 3; ++t)
        #pragma unroll
        for (int nt = 0; nt < 2; ++nt)
            acc[t][nt] = biasv[t];

    #pragma unroll
    for (int nt = 0; nt < 2; ++nt) {
        s16x8 bf[4];
        #pragma unroll
        for (int ks = 0; ks < 4; ++ks)
            bf[ks] = *(const s16x8*)&xsT[(nt * 16 + nn) * 136 + ks * 32 + quad * 8];
        #pragma unroll
        for (int t = 0; t < 3; ++t)
            if (live[t])
                #pragma unroll
                for (int ks = 0; ks < 4; ++ks)
                    acc[t][nt] = __builtin_amdgcn_mfma_f32_16x16x32_bf16(af[t][ks], bf[ks], acc[t][nt], 0, 0, 0);
    }

    // V-slot key permutation: swap bits 2<->3 of (key%16)
    const int slot = (nn & 3) | ((nn & 4) << 1) | ((nn & 8) >> 1);

    #pragma unroll
    for (int t = 0; t < 3; ++t) {
        if (!live[t]) continue;
        const int rid = 3 * w + t;
        #pragma unroll
        for (int nt = 0; nt < 2; ++nt) {
            if (rid < 8) {
                // V rows -> LDS staging tile (layout == global vt tile)
                #pragma unroll
                for (int r = 0; r < 4; ++r) {
                    int row = rid * 16 + quad * 4 + r;
                    vstage[(((nt << 2) | (row >> 5)) << 9) + ((row & 31) << 4) + slot]
                        = bf16s(acc[t][nt][r]);
                }
            } else {
                short4 pk;
                pk.x = bf16s(acc[t][nt][0]);
                pk.y = bf16s(acc[t][nt][1]);
                pk.z = bf16s(acc[t][nt][2]);
                pk.w = bf16s(acc[t][nt][3]);
                int n = n0 + nt * 16 + nn;
                short* dst = (rid == 8 ? qb : kb) +
                             ((size_t)(b * NNPOS) + n) * 16 + quad * 4;
                *reinterpret_cast<short4*>(dst) = pk;
            }
        }
    }
    __syncthreads();

    // coalesced copy-out: 8 KB tile, 256 threads x 2 x 16B
    {
        short* vdst = vt + ((size_t)(b * 256) + (n0 >> 4)) * 2048;
        #pragma unroll
        for (int p = 0; p < 2; ++p) {
            int off = (tid + p * 256) * 8;
            *(s16x8*)&vdst[off] = *(const s16x8*)&vstage[off];
        }
    }
}

// ------------------------------------------------------------------
// Kernel 2: flash attention, S^T formulation, mfma 32x32x16.
// Barrier-free, LDS-free, shuffle-free (slot-permuted V), occupancy-
// first: nq=1 (32 q/wave, acc=64 VGPR), peak live regs ~158 -> 3
// waves/SIMD via __launch_bounds__(256,3).
// R10: KSP=6 -> grid (6,32,NB)=768 blocks = exactly 3 resident/CU
// (no queued-block tail). Uneven split: s<4 -> 704 keys (11 iters),
// s=4,5 -> 640 keys (10 iters).
// R10: K A-frags for iter+1 prefetched right after the score MFMAs
// consume the current ones (hides ~200cy L2 latency; +8 VGPR only --
// the R9 spill was the 32-reg V prefetch, not this).
// R10: s_setprio(1) around PV MFMA clusters (T5: phase-diverse waves).
// ------------------------------------------------------------------
__global__ __launch_bounds__(256, 3) void attn_kernel(
    const short* __restrict__ qb, const short* __restrict__ kb,
    const short* __restrict__ vt,
    unsigned short* __restrict__ Ow, float* __restrict__ lw)
{
    const int s   = blockIdx.x;    // key split 0..5
    const int b   = blockIdx.z;
    const int tid = threadIdx.x;
    const int w = tid >> 6, lane = tid & 63, h = lane >> 5, c31 = lane & 31;

    const int q0 = (blockIdx.y * 4 + w) * 32;   // wave's 32-query tile

    s16x8 bq = *(const s16x8*)(qb + ((size_t)(b * NNPOS) + q0 + c31) * 16 + h * 8);

    f32x16 acc[4];
    #pragma unroll
    for (int ct = 0; ct < 4; ++ct)
        #pragma unroll
        for (int r = 0; r < 16; ++r) acc[ct][r] = 0.0f;
    float lp0 = 0.f, lp1 = 0.f;

    const short* kbp = kb + (size_t)(b * NNPOS) * 16;
    const short* vbp = vt + (size_t)b * (256 * 4 * 512);
    const int nit    = (s < 4) ? 11 : 10;
    const int mbase  = (s < 4) ? s * 704 : 2816 + (s - 4) * 640;
    const int kgbase = mbase >> 4;
    const int voff = (c31 << 4) + (h << 3);

    f32x16 z;
    #pragma unroll
    for (int r = 0; r < 16; ++r) z[r] = 0.0f;

    // K prefetch for iter 0
    int m0 = mbase;
    s16x8 ak0 = *(const s16x8*)(kbp + (size_t)(m0      + c31) * 16 + h * 8);
    s16x8 ak1 = *(const s16x8*)(kbp + (size_t)(m0 + 32 + c31) * 16 + h * 8);

    for (int it = 0; it < nit; ++it) {
        const int kg0 = kgbase + it * 4;

        // V groups 0,1
        s16x8 vb01[2][4];
        #pragma unroll
        for (int p = 0; p < 2; ++p)
            #pragma unroll
            for (int ct = 0; ct < 4; ++ct)
                vb01[p][ct] = *(const s16x8*)(vbp +
                    (((size_t)(kg0 + p) * 4 + ct) << 9) + voff);

        // scores (K frags were prefetched last iter -> no vmem wait here)
        f32x16 s0 = __builtin_amdgcn_mfma_f32_32x32x16_bf16(ak0, bq, z, 0, 0, 0);
        f32x16 s1 = __builtin_amdgcn_mfma_f32_32x32x16_bf16(ak1, bq, z, 0, 0, 0);

        // prefetch next iter's K (ak0/ak1 dead after the score MFMAs issue)
        if (it + 1 < nit) {
            m0 += 64;
            ak0 = *(const s16x8*)(kbp + (size_t)(m0      + c31) * 16 + h * 8);
            ak1 = *(const s16x8*)(kbp + (size_t)(m0 + 32 + c31) * 16 + h * 8);
        }

        // exp + pack into all 4 PV A-frags (slot-permuted V: no shuffle)
        s16x8 pa[4];
        #pragma unroll
        for (int p = 0; p < 4; ++p) {
            const f32x16& sv = (p < 2) ? s0 : s1;
            const int off = (p & 1) * 8;
            union { int i[4]; s16x8 v; } u;
            #pragma unroll
            for (int j = 0; j < 4; ++j) {
                float p0 = exp2fast(sv[off + 2 * j]);
                float p1 = exp2fast(sv[off + 2 * j + 1]);
                if (j & 1) lp1 += p0 + p1; else lp0 += p0 + p1;
                u.i[j] = packbf2(p0, p1);
            }
            pa[p] = u.v;
        }

        // PV groups 0,1
        __builtin_amdgcn_s_setprio(1);
        #pragma unroll
        for (int p = 0; p < 2; ++p)
            #pragma unroll
            for (int ct = 0; ct < 4; ++ct)
                acc[ct] = __builtin_amdgcn_mfma_f32_32x32x16_bf16(
                    pa[p], vb01[p][ct], acc[ct], 0, 0, 0);
        __builtin_amdgcn_s_setprio(0);

        // V groups 2,3 (loaded after vb01 is dead: no register-peak growth)
        s16x8 vb23[2][4];
        #pragma unroll
        for (int p = 0; p < 2; ++p)
            #pragma unroll
            for (int ct = 0; ct < 4; ++ct)
                vb23[p][ct] = *(const s16x8*)(vbp +
                    (((size_t)(kg0 + 2 + p) * 4 + ct) << 9) + voff);

        __builtin_amdgcn_s_setprio(1);
        #pragma unroll
        for (int p = 0; p < 2; ++p)
            #pragma unroll
            for (int ct = 0; ct < 4; ++ct)
                acc[ct] = __builtin_amdgcn_mfma_f32_32x32x16_bf16(
                    pa[2 + p], vb23[p][ct], acc[ct], 0, 0, 0);
        __builtin_amdgcn_s_setprio(0);
    }

    float lp = lp0 + lp1;
    lp += __shfl_xor(lp, 32, 64);
    if (lane < 32)
        lw[((size_t)(b * KSP + s)) * NNPOS + q0 + c31] = lp;

    // O partial: [b][s][n][c] bf16
    #pragma unroll
    for (int ct = 0; ct < 4; ++ct)
        #pragma unroll
        for (int r = 0; r < 16; ++r) {
            int q = q0 + (r & 3) + 8 * (r >> 2) + 4 * h;
            Ow[(((size_t)(b * KSP + s)) * NNPOS + q) * NC + ct * 32 + c31] =
                (unsigned short)bf16s(acc[ct][r]);
        }
}

// ------------------------------------------------------------------
// Kernel 3: combine split-K partials + epilogue.
// R10: phase-1 Ow loads widened to 16B (wave reads 1KB contiguous),
// phase-2 float4 x-load + float4 out-store (was scalar 4B), reciprocal
// of lsum hoisted.
// out[b][c][n] = gamma * (sum_s O[b][s][n][c]) / (sum_s l[b][s][n]) + x
// ------------------------------------------------------------------
__global__ __launch_bounds__(256) void combine_kernel(
    const unsigned short* __restrict__ Ow, const float* __restrict__ lw,
    const float* __restrict__ x, const float* __restrict__ gamma,
    float* __restrict__ out)
{
    const int n0  = blockIdx.x * 64;
    const int b   = blockIdx.y;
    const int tid = threadIdx.x;

    __shared__ float ot[128 * 65 + 64];
    float* lsum = ot + 128 * 65;

    if (tid < 64) {
        float sl = 0.f;
        #pragma unroll
        for (int sI = 0; sI < KSP; ++sI)
            sl += lw[((size_t)(b * KSP + sI)) * NNPOS + n0 + tid];
        lsum[tid] = 1.0f / sl;
    }
    __syncthreads();

    #pragma unroll
    for (int p = 0; p < 4; ++p) {
        int e = tid + p * 256;          // over 16 c-octs x 64 n
        int co = e & 15, n = e >> 4;
        float a[8] = {0.f, 0.f, 0.f, 0.f, 0.f, 0.f, 0.f, 0.f};
        #pragma unroll
        for (int sI = 0; sI < KSP; ++sI) {
            const unsigned short* src = Ow +
                (((size_t)(b * KSP + sI)) * NNPOS + n0 + n) * NC + co * 8;
            union { s16x8 v; unsigned short us[8]; } u;
            u.v = *(const s16x8*)src;
            #pragma unroll
            for (int j = 0; j < 8; ++j) a[j] += bf2f(u.us[j]);
        }
        float inv = lsum[n];
        #pragma unroll
        for (int j = 0; j < 8; ++j)
            ot[(co * 8 + j) * 65 + n] = a[j] * inv;
    }
    __syncthreads();

    const float g = gamma[0];
    #pragma unroll
    for (int p = 0; p < 8; ++p) {
        int e = tid + p * 256;          // over 128 c x 16 n-quads
        int nq = e & 15, c = e >> 4;
        size_t a = ((size_t)(b * NC + c)) * NNPOS + n0 + nq * 4;
        float4 xv = *(const float4*)&x[a];
        float4 o;
        o.x = g * ot[c * 65 + nq * 4]     + xv.x;
        o.y = g * ot[c * 65 + nq * 4 + 1] + xv.y;
        o.z = g * ot[c * 65 + nq * 4 + 2] + xv.z;
        o.w = g * ot[c * 65 + nq * 4 + 3] + xv.w;
        *(float4*)&out[a] = o;
    }
}

// ------------------------------------------------------------------
extern "C" void kernel_launch(void* const* d_in, const int* in_sizes, int n_in,
                              void* d_out, int out_size, void* d_ws, size_t ws_size,
                              hipStream_t stream) {
    const float* x     = (const float*)d_in[0];
    const float* wq    = (const float*)d_in[1];
    const float* bq    = (const float*)d_in[2];
    const float* wk    = (const float*)d_in[3];
    const float* bk    = (const float*)d_in[4];
    const float* wv    = (const float*)d_in[5];
    const float* bv    = (const float*)d_in[6];
    const float* gamma = (const float*)d_in[7];
    float* out = (float*)d_out;

    // ws: qb 512KB | kb 512KB | vt 4MB | Ow 25.2MB | lw 384KB
    short* qb = (short*)d_ws;
    short* kb = qb + (size_t)NB * NNPOS * 16;
    short* vt = kb + (size_t)NB * NNPOS * 16;
    unsigned short* Ow = (unsigned short*)(vt + (size_t)NB * NC * NNPOS);
    float* lw = (float*)(Ow + (size_t)NB * KSP * NNPOS * NC);

    qkv_kernel<<<dim3(128, NB), 256, 0, stream>>>(x, wq, bq, wk, bk, wv, bv, qb, kb, vt);
    attn_kernel<<<dim3(KSP, 32, NB), 256, 0, stream>>>(qb, kb, vt, Ow, lw);
    combine_kernel<<<dim3(NNPOS / 64, NB), 256, 0, stream>>>(Ow, lw, x, gamma, out);
}

// Round 2
// 114.289 us; speedup vs baseline: 1.0482x; 1.0482x over previous
//
#include <hip/hip_runtime.h>
#include <hip/hip_bf16.h>

typedef float f32x4  __attribute__((ext_vector_type(4)));
typedef float f32x16 __attribute__((ext_vector_type(16)));
typedef short s16x8  __attribute__((ext_vector_type(8)));
typedef unsigned int u32;

#define NB 4
#define NC 128
#define NNPOS 4096
#define KSP 6          // grid 768 = 3 blocks/CU exactly
#define LOG2E 1.44269504088896f

__device__ __forceinline__ short bf16s(float x) {
    __hip_bfloat16 h = __float2bfloat16(x);
    return *reinterpret_cast<short*>(&h);
}
__device__ __forceinline__ int packbf2(float lo, float hi) {
    __hip_bfloat162 t = __float22bfloat162_rn(float2{lo, hi});
    return *reinterpret_cast<int*>(&t);
}
__device__ __forceinline__ float bf2f(unsigned short u) {
    unsigned int v = ((unsigned int)u) << 16;
    return *reinterpret_cast<float*>(&v);
}
__device__ __forceinline__ float exp2fast(float x) {
    return __builtin_amdgcn_exp2f(x);   // native v_exp_f32 (base 2)
}
__device__ __forceinline__ void gload_lds16(const short* g, short* l) {
    __builtin_amdgcn_global_load_lds(
        (const __attribute__((address_space(1))) u32*)g,
        (__attribute__((address_space(3))) u32*)l, 16, 0, 0);
}

// ------------------------------------------------------------------
// Kernel 1: QKV projection via bf16 MFMA 16x16x32.
// vt layout (R11): linear-lane order so attn can stage it with
// global_load_lds (wave-uniform base + lane*16B, m104):
//   short_idx = ((b*256+kg)*4 + ct)*512 + (slot>>3)*256 + (c&31)*8 + (slot&7)
// where slot = swap-bits-2,3 of (key%16). Lane l = h*32+c31 of the attn
// wave then reads its PV B-frag at exactly l*16 bytes within each
// (kg,ct) 1KB slab -> staging is linear, ds_read_b128 contiguous.
// ------------------------------------------------------------------
__global__ __launch_bounds__(256) void qkv_kernel(
    const float* __restrict__ x,
    const float* __restrict__ wq, const float* __restrict__ bq,
    const float* __restrict__ wk, const float* __restrict__ bk,
    const float* __restrict__ wv, const float* __restrict__ bv,
    short* __restrict__ qb, short* __restrict__ kb, short* __restrict__ vt)
{
    const int n0  = blockIdx.x * 32;
    const int b   = blockIdx.y;
    const int tid = threadIdx.x;
    const int w = tid >> 6, lane = tid & 63, quad = lane >> 4, nn = lane & 15;

    __shared__ __align__(16) short xsT[32 * 136];
    __shared__ __align__(16) short vstage[4096];   // 2 kg x 4 ct x 512

    #pragma unroll
    for (int p = 0; p < 4; ++p) {
        int idx = tid + p * 256;
        int cc = idx >> 3, n4 = (idx & 7) * 4;
        f32x4 xv = *(const f32x4*)&x[((size_t)(b * NC + cc)) * NNPOS + n0 + n4];
        #pragma unroll
        for (int j = 0; j < 4; ++j)
            xsT[(n4 + j) * 136 + cc] = bf16s(xv[j]);
    }

    s16x8 af[3][4];
    bool  live[3];
    f32x4 biasv[3];
    #pragma unroll
    for (int t = 0; t < 3; ++t) {
        int rid = 3 * w + t;
        int R   = rid * 16;
        const float* wsrc = nullptr; const float* bsrc = nullptr; int row0 = 0;
        float scale = 1.0f;
        if (rid < 8)        { wsrc = wv; bsrc = bv; row0 = R; }
        else if (rid == 8)  { wsrc = wq; bsrc = bq; row0 = 0; scale = LOG2E; }
        else if (rid == 10) { wsrc = wk; bsrc = bk; row0 = 0; }
        live[t] = (wsrc != nullptr);
        #pragma unroll
        for (int r = 0; r < 4; ++r)
            biasv[t][r] = live[t] ? scale * bsrc[row0 + quad * 4 + r] : 0.0f;
        if (live[t]) {
            #pragma unroll
            for (int ks = 0; ks < 4; ++ks) {
                const float* src = wsrc + (size_t)(row0 + nn) * NC + ks * 32 + quad * 8;
                f32x4 wa = *(const f32x4*)src;
                f32x4 wb = *(const f32x4*)(src + 4);
                s16x8 f;
                #pragma unroll
                for (int j = 0; j < 4; ++j) {
                    f[j]     = bf16s(scale * wa[j]);
                    f[j + 4] = bf16s(scale * wb[j]);
                }
                af[t][ks] = f;
            }
        }
    }
    __syncthreads();

    f32x4 acc[3][2];
    #pragma unroll
    for (int t = 0; t < 3; ++t)
        #pragma unroll
        for (int nt = 0; nt < 2; ++nt)
            acc[t][nt] = biasv[t];

    #pragma unroll
    for (int nt = 0; nt < 2; ++nt) {
        s16x8 bf[4];
        #pragma unroll
        for (int ks = 0; ks < 4; ++ks)
            bf[ks] = *(const s16x8*)&xsT[(nt * 16 + nn) * 136 + ks * 32 + quad * 8];
        #pragma unroll
        for (int t = 0; t < 3; ++t)
            if (live[t])
                #pragma unroll
                for (int ks = 0; ks < 4; ++ks)
                    acc[t][nt] = __builtin_amdgcn_mfma_f32_16x16x32_bf16(af[t][ks], bf[ks], acc[t][nt], 0, 0, 0);
    }

    // V-slot key permutation: swap bits 2<->3 of (key%16)
    const int slot = (nn & 3) | ((nn & 4) << 1) | ((nn & 8) >> 1);

    #pragma unroll
    for (int t = 0; t < 3; ++t) {
        if (!live[t]) continue;
        const int rid = 3 * w + t;
        #pragma unroll
        for (int nt = 0; nt < 2; ++nt) {
            if (rid < 8) {
                // V rows -> LDS staging tile (layout == global vt tile)
                #pragma unroll
                for (int r = 0; r < 4; ++r) {
                    int row = rid * 16 + quad * 4 + r;
                    vstage[(((nt << 2) | (row >> 5)) << 9) +
                           ((slot >> 3) << 8) + ((row & 31) << 3) + (slot & 7)]
                        = bf16s(acc[t][nt][r]);
                }
            } else {
                short4 pk;
                pk.x = bf16s(acc[t][nt][0]);
                pk.y = bf16s(acc[t][nt][1]);
                pk.z = bf16s(acc[t][nt][2]);
                pk.w = bf16s(acc[t][nt][3]);
                int n = n0 + nt * 16 + nn;
                short* dst = (rid == 8 ? qb : kb) +
                             ((size_t)(b * NNPOS) + n) * 16 + quad * 4;
                *reinterpret_cast<short4*>(dst) = pk;
            }
        }
    }
    __syncthreads();

    // coalesced copy-out: 8 KB tile, 256 threads x 2 x 16B
    {
        short* vdst = vt + ((size_t)(b * 256) + (n0 >> 4)) * 2048;
        #pragma unroll
        for (int p = 0; p < 2; ++p) {
            int off = (tid + p * 256) * 8;
            *(s16x8*)&vdst[off] = *(const s16x8*)&vstage[off];
        }
    }
}

// ------------------------------------------------------------------
// Kernel 2: flash attention, S^T formulation, mfma 32x32x16.
// R11: the block's 4 waves share one V stream staged in LDS via
// global_load_lds (double-buffered, 32KB) instead of 4 private global
// streams -> V L2 traffic 512MB -> 128MB. One __syncthreads per iter;
// stage for it+1 issued at iter top so HBM/L2 latency hides under
// scores+exp+PV. K stays per-wave in registers with 1-iter prefetch.
// setprio dropped (R10 regression suspect; barriers make waves more
// lockstep -> m190 regime). VGPR peak drops vs R10 (no vb01/vb23
// register tiles) -> still 3 waves/SIMD via __launch_bounds__(256,3).
// ------------------------------------------------------------------
__global__ __launch_bounds__(256, 3) void attn_kernel(
    const short* __restrict__ qb, const short* __restrict__ kb,
    const short* __restrict__ vt,
    unsigned short* __restrict__ Ow, float* __restrict__ lw)
{
    const int s   = blockIdx.x;    // key split 0..5
    const int b   = blockIdx.z;
    const int tid = threadIdx.x;
    const int w = tid >> 6, lane = tid & 63, h = lane >> 5, c31 = lane & 31;

    const int q0 = (blockIdx.y * 4 + w) * 32;   // wave's 32-query tile

    __shared__ __align__(16) short vlds[2][8192];   // 2 x 16KB (64 keys x 128c)

    s16x8 bq = *(const s16x8*)(qb + ((size_t)(b * NNPOS) + q0 + c31) * 16 + h * 8);

    f32x16 acc[4];
    #pragma unroll
    for (int ct = 0; ct < 4; ++ct)
        #pragma unroll
        for (int r = 0; r < 16; ++r) acc[ct][r] = 0.0f;
    float lp0 = 0.f, lp1 = 0.f;

    const short* kbp = kb + (size_t)(b * NNPOS) * 16;
    const int nit    = (s < 4) ? 11 : 10;
    const int mbase  = (s < 4) ? s * 704 : 2816 + (s - 4) * 640;
    const short* vtile = vt + (size_t)b * (NC * NNPOS) + ((size_t)(mbase >> 4) << 11);

    f32x16 z;
    #pragma unroll
    for (int r = 0; r < 16; ++r) z[r] = 0.0f;

    // prologue: stage iter 0 into buf 0; prefetch K for iter 0
    #pragma unroll
    for (int j = 0; j < 4; ++j)
        gload_lds16(vtile + (tid << 3) + (j << 11),
                    &vlds[0][0] + (tid << 3) + (j << 11));
    int m0 = mbase;
    s16x8 ak0 = *(const s16x8*)(kbp + (size_t)(m0      + c31) * 16 + h * 8);
    s16x8 ak1 = *(const s16x8*)(kbp + (size_t)(m0 + 32 + c31) * 16 + h * 8);
    __syncthreads();

    int buf = 0;
    for (int it = 0; it < nit; ++it) {
        // issue next-tile V staging into the other buffer (latency hidden
        // under this iter's compute; completion enforced by the barrier)
        if (it + 1 < nit) {
            const short* src = vtile + (((size_t)(it + 1)) << 13);
            short* dst = &vlds[buf ^ 1][0];
            #pragma unroll
            for (int j = 0; j < 4; ++j)
                gload_lds16(src + (tid << 3) + (j << 11),
                            dst + (tid << 3) + (j << 11));
        }

        // scores (K frags prefetched last iter)
        f32x16 s0 = __builtin_amdgcn_mfma_f32_32x32x16_bf16(ak0, bq, z, 0, 0, 0);
        f32x16 s1 = __builtin_amdgcn_mfma_f32_32x32x16_bf16(ak1, bq, z, 0, 0, 0);

        // prefetch next iter's K
        if (it + 1 < nit) {
            m0 += 64;
            ak0 = *(const s16x8*)(kbp + (size_t)(m0      + c31) * 16 + h * 8);
            ak1 = *(const s16x8*)(kbp + (size_t)(m0 + 32 + c31) * 16 + h * 8);
        }

        // exp + pack into all 4 PV A-frags (slot-permuted V: no shuffle)
        s16x8 pa[4];
        #pragma unroll
        for (int p = 0; p < 4; ++p) {
            const f32x16& sv = (p < 2) ? s0 : s1;
            const int off = (p & 1) * 8;
            union { int i[4]; s16x8 v; } u;
            #pragma unroll
            for (int j = 0; j < 4; ++j) {
                float p0 = exp2fast(sv[off + 2 * j]);
                float p1 = exp2fast(sv[off + 2 * j + 1]);
                if (j & 1) lp1 += p0 + p1; else lp0 += p0 + p1;
                u.i[j] = packbf2(p0, p1);
            }
            pa[p] = u.v;
        }

        // PV from shared LDS V (16 contiguous ds_read_b128 per wave,
        // compiler interleaves with MFMA via counted lgkmcnt)
        const short* vb = &vlds[buf][0];
        #pragma unroll
        for (int p = 0; p < 4; ++p)
            #pragma unroll
            for (int ct = 0; ct < 4; ++ct) {
                s16x8 vf = *(const s16x8*)&vb[((p * 4 + ct) << 9) + (lane << 3)];
                acc[ct] = __builtin_amdgcn_mfma_f32_32x32x16_bf16(
                    pa[p], vf, acc[ct], 0, 0, 0);
            }

        __syncthreads();   // staging of it+1 complete; reads of buf done
        buf ^= 1;
    }

    float lp = lp0 + lp1;
    lp += __shfl_xor(lp, 32, 64);
    if (lane < 32)
        lw[((size_t)(b * KSP + s)) * NNPOS + q0 + c31] = lp;

    // O partial: [b][s][n][c] bf16
    #pragma unroll
    for (int ct = 0; ct < 4; ++ct)
        #pragma unroll
        for (int r = 0; r < 16; ++r) {
            int q = q0 + (r & 3) + 8 * (r >> 2) + 4 * h;
            Ow[(((size_t)(b * KSP + s)) * NNPOS + q) * NC + ct * 32 + c31] =
                (unsigned short)bf16s(acc[ct][r]);
        }
}

// ------------------------------------------------------------------
// Kernel 3: combine split-K partials + epilogue.
// out[b][c][n] = gamma * (sum_s O[b][s][n][c]) / (sum_s l[b][s][n]) + x
// ------------------------------------------------------------------
__global__ __launch_bounds__(256) void combine_kernel(
    const unsigned short* __restrict__ Ow, const float* __restrict__ lw,
    const float* __restrict__ x, const float* __restrict__ gamma,
    float* __restrict__ out)
{
    const int n0  = blockIdx.x * 64;
    const int b   = blockIdx.y;
    const int tid = threadIdx.x;

    __shared__ float ot[128 * 65 + 64];
    float* lsum = ot + 128 * 65;

    if (tid < 64) {
        float sl = 0.f;
        #pragma unroll
        for (int sI = 0; sI < KSP; ++sI)
            sl += lw[((size_t)(b * KSP + sI)) * NNPOS + n0 + tid];
        lsum[tid] = 1.0f / sl;
    }
    __syncthreads();

    #pragma unroll
    for (int p = 0; p < 4; ++p) {
        int e = tid + p * 256;          // over 16 c-octs x 64 n
        int co = e & 15, n = e >> 4;
        float a[8] = {0.f, 0.f, 0.f, 0.f, 0.f, 0.f, 0.f, 0.f};
        #pragma unroll
        for (int sI = 0; sI < KSP; ++sI) {
            const unsigned short* src = Ow +
                (((size_t)(b * KSP + sI)) * NNPOS + n0 + n) * NC + co * 8;
            union { s16x8 v; unsigned short us[8]; } u;
            u.v = *(const s16x8*)src;
            #pragma unroll
            for (int j = 0; j < 8; ++j) a[j] += bf2f(u.us[j]);
        }
        float inv = lsum[n];
        #pragma unroll
        for (int j = 0; j < 8; ++j)
            ot[(co * 8 + j) * 65 + n] = a[j] * inv;
    }
    __syncthreads();

    const float g = gamma[0];
    #pragma unroll
    for (int p = 0; p < 8; ++p) {
        int e = tid + p * 256;          // over 128 c x 16 n-quads
        int nq = e & 15, c = e >> 4;
        size_t a = ((size_t)(b * NC + c)) * NNPOS + n0 + nq * 4;
        float4 xv = *(const float4*)&x[a];
        float4 o;
        o.x = g * ot[c * 65 + nq * 4]     + xv.x;
        o.y = g * ot[c * 65 + nq * 4 + 1] + xv.y;
        o.z = g * ot[c * 65 + nq * 4 + 2] + xv.z;
        o.w = g * ot[c * 65 + nq * 4 + 3] + xv.w;
        *(float4*)&out[a] = o;
    }
}

// ------------------------------------------------------------------
extern "C" void kernel_launch(void* const* d_in, const int* in_sizes, int n_in,
                              void* d_out, int out_size, void* d_ws, size_t ws_size,
                              hipStream_t stream) {
    const float* x     = (const float*)d_in[0];
    const float* wq    = (const float*)d_in[1];
    const float* bq    = (const float*)d_in[2];
    const float* wk    = (const float*)d_in[3];
    const float* bk    = (const float*)d_in[4];
    const float* wv    = (const float*)d_in[5];
    const float* bv    = (const float*)d_in[6];
    const float* gamma = (const float*)d_in[7];
    float* out = (float*)d_out;

    // ws: qb 512KB | kb 512KB | vt 4MB | Ow 25.2MB | lw 384KB
    short* qb = (short*)d_ws;
    short* kb = qb + (size_t)NB * NNPOS * 16;
    short* vt = kb + (size_t)NB * NNPOS * 16;
    unsigned short* Ow = (unsigned short*)(vt + (size_t)NB * NC * NNPOS);
    float* lw = (float*)(Ow + (size_t)NB * KSP * NNPOS * NC);

    qkv_kernel<<<dim3(128, NB), 256, 0, stream>>>(x, wq, bq, wk, bk, wv, bv, qb, kb, vt);
    attn_kernel<<<dim3(KSP, 32, NB), 256, 0, stream>>>(qb, kb, vt, Ow, lw);
    combine_kernel<<<dim3(NNPOS / 64, NB), 256, 0, stream>>>(Ow, lw, x, gamma, out);
}

// Round 3
// 113.116 us; speedup vs baseline: 1.0591x; 1.0104x over previous
//
#include <hip/hip_runtime.h>
#include <hip/hip_bf16.h>

typedef float f32x4  __attribute__((ext_vector_type(4)));
typedef float f32x16 __attribute__((ext_vector_type(16)));
typedef short s16x8  __attribute__((ext_vector_type(8)));
typedef unsigned int u32;

#define NB 4
#define NC 128
#define NNPOS 4096
#define KSP 8          // R12: 8 splits, nq=2 -> 2048 waves = 2/SIMD, 512 blocks = 2/CU exact
#define LOG2E 1.44269504088896f

__device__ __forceinline__ short bf16s(float x) {
    __hip_bfloat16 h = __float2bfloat16(x);
    return *reinterpret_cast<short*>(&h);
}
__device__ __forceinline__ int packbf2(float lo, float hi) {
    __hip_bfloat162 t = __float22bfloat162_rn(float2{lo, hi});
    return *reinterpret_cast<int*>(&t);
}
__device__ __forceinline__ float bf2f(unsigned short u) {
    unsigned int v = ((unsigned int)u) << 16;
    return *reinterpret_cast<float*>(&v);
}
__device__ __forceinline__ float exp2fast(float x) {
    return __builtin_amdgcn_exp2f(x);   // native v_exp_f32 (base 2)
}
__device__ __forceinline__ void gload_lds16(const short* g, short* l) {
    __builtin_amdgcn_global_load_lds(
        (const __attribute__((address_space(1))) u32*)g,
        (__attribute__((address_space(3))) u32*)l, 16, 0, 0);
}

// ------------------------------------------------------------------
// Kernel 1: QKV projection via bf16 MFMA 16x16x32 (unchanged from R11).
// vt layout: linear-lane order so attn can stage it with
// global_load_lds (wave-uniform base + lane*16B, m104):
//   short_idx = ((b*256+kg)*4 + ct)*512 + (slot>>3)*256 + (c&31)*8 + (slot&7)
// where slot = swap-bits-2,3 of (key%16). Lane l of the attn wave reads
// its PV B-frag at exactly l*16 bytes within each (kg,ct) 1KB slab.
// ------------------------------------------------------------------
__global__ __launch_bounds__(256) void qkv_kernel(
    const float* __restrict__ x,
    const float* __restrict__ wq, const float* __restrict__ bq,
    const float* __restrict__ wk, const float* __restrict__ bk,
    const float* __restrict__ wv, const float* __restrict__ bv,
    short* __restrict__ qb, short* __restrict__ kb, short* __restrict__ vt)
{
    const int n0  = blockIdx.x * 32;
    const int b   = blockIdx.y;
    const int tid = threadIdx.x;
    const int w = tid >> 6, lane = tid & 63, quad = lane >> 4, nn = lane & 15;

    __shared__ __align__(16) short xsT[32 * 136];
    __shared__ __align__(16) short vstage[4096];   // 2 kg x 4 ct x 512

    #pragma unroll
    for (int p = 0; p < 4; ++p) {
        int idx = tid + p * 256;
        int cc = idx >> 3, n4 = (idx & 7) * 4;
        f32x4 xv = *(const f32x4*)&x[((size_t)(b * NC + cc)) * NNPOS + n0 + n4];
        #pragma unroll
        for (int j = 0; j < 4; ++j)
            xsT[(n4 + j) * 136 + cc] = bf16s(xv[j]);
    }

    s16x8 af[3][4];
    bool  live[3];
    f32x4 biasv[3];
    #pragma unroll
    for (int t = 0; t < 3; ++t) {
        int rid = 3 * w + t;
        int R   = rid * 16;
        const float* wsrc = nullptr; const float* bsrc = nullptr; int row0 = 0;
        float scale = 1.0f;
        if (rid < 8)        { wsrc = wv; bsrc = bv; row0 = R; }
        else if (rid == 8)  { wsrc = wq; bsrc = bq; row0 = 0; scale = LOG2E; }
        else if (rid == 10) { wsrc = wk; bsrc = bk; row0 = 0; }
        live[t] = (wsrc != nullptr);
        #pragma unroll
        for (int r = 0; r < 4; ++r)
            biasv[t][r] = live[t] ? scale * bsrc[row0 + quad * 4 + r] : 0.0f;
        if (live[t]) {
            #pragma unroll
            for (int ks = 0; ks < 4; ++ks) {
                const float* src = wsrc + (size_t)(row0 + nn) * NC + ks * 32 + quad * 8;
                f32x4 wa = *(const f32x4*)src;
                f32x4 wb = *(const f32x4*)(src + 4);
                s16x8 f;
                #pragma unroll
                for (int j = 0; j < 4; ++j) {
                    f[j]     = bf16s(scale * wa[j]);
                    f[j + 4] = bf16s(scale * wb[j]);
                }
                af[t][ks] = f;
            }
        }
    }
    __syncthreads();

    f32x4 acc[3][2];
    #pragma unroll
    for (int t = 0; t < 3; ++t)
        #pragma unroll
        for (int nt = 0; nt < 2; ++nt)
            acc[t][nt] = biasv[t];

    #pragma unroll
    for (int nt = 0; nt < 2; ++nt) {
        s16x8 bf[4];
        #pragma unroll
        for (int ks = 0; ks < 4; ++ks)
            bf[ks] = *(const s16x8*)&xsT[(nt * 16 + nn) * 136 + ks * 32 + quad * 8];
        #pragma unroll
        for (int t = 0; t < 3; ++t)
            if (live[t])
                #pragma unroll
                for (int ks = 0; ks < 4; ++ks)
                    acc[t][nt] = __builtin_amdgcn_mfma_f32_16x16x32_bf16(af[t][ks], bf[ks], acc[t][nt], 0, 0, 0);
    }

    // V-slot key permutation: swap bits 2<->3 of (key%16)
    const int slot = (nn & 3) | ((nn & 4) << 1) | ((nn & 8) >> 1);

    #pragma unroll
    for (int t = 0; t < 3; ++t) {
        if (!live[t]) continue;
        const int rid = 3 * w + t;
        #pragma unroll
        for (int nt = 0; nt < 2; ++nt) {
            if (rid < 8) {
                // V rows -> LDS staging tile (layout == global vt tile)
                #pragma unroll
                for (int r = 0; r < 4; ++r) {
                    int row = rid * 16 + quad * 4 + r;
                    vstage[(((nt << 2) | (row >> 5)) << 9) +
                           ((slot >> 3) << 8) + ((row & 31) << 3) + (slot & 7)]
                        = bf16s(acc[t][nt][r]);
                }
            } else {
                short4 pk;
                pk.x = bf16s(acc[t][nt][0]);
                pk.y = bf16s(acc[t][nt][1]);
                pk.z = bf16s(acc[t][nt][2]);
                pk.w = bf16s(acc[t][nt][3]);
                int n = n0 + nt * 16 + nn;
                short* dst = (rid == 8 ? qb : kb) +
                             ((size_t)(b * NNPOS) + n) * 16 + quad * 4;
                *reinterpret_cast<short4*>(dst) = pk;
            }
        }
    }
    __syncthreads();

    // coalesced copy-out: 8 KB tile, 256 threads x 2 x 16B
    {
        short* vdst = vt + ((size_t)(b * 256) + (n0 >> 4)) * 2048;
        #pragma unroll
        for (int p = 0; p < 2; ++p) {
            int off = (tid + p * 256) * 8;
            *(s16x8*)&vdst[off] = *(const s16x8*)&vstage[off];
        }
    }
}

// ------------------------------------------------------------------
// Kernel 2: flash attention, S^T formulation, mfma 32x32x16.
// R12: nq=2 -- each wave owns TWO 32-query tiles sharing every LDS V
// fragment (one ds_read_b128 feeds 2 PV MFMAs). Halves the CU LDS-read
// pipe load (R11's critical path: 12w x 16rd x 12cy = 2304cy/round vs
// MFMA 1728cy). Now MFMA-bound: per round 8w x 36mfma x 8cy = 2304cy
// vs LDS 1536cy. KSP=8, grid (8,16,4)=512 blocks = 2/CU, 2048 waves =
// 2/SIMD, VGPR peak ~220 < 256 (launch_bounds 256,2).
// V staged double-buffered in LDS via global_load_lds (32KB/block);
// one barrier per iter; K per-wave in regs with 1-iter prefetch.
// ------------------------------------------------------------------
__global__ __launch_bounds__(256, 2) void attn_kernel(
    const short* __restrict__ qb, const short* __restrict__ kb,
    const short* __restrict__ vt,
    unsigned short* __restrict__ Ow, float* __restrict__ lw)
{
    const int s   = blockIdx.x;    // key split 0..7
    const int b   = blockIdx.z;
    const int tid = threadIdx.x;
    const int w = tid >> 6, lane = tid & 63, h = lane >> 5, c31 = lane & 31;

    const int q0 = (blockIdx.y * 4 + w) * 64;   // wave's 64-query super-tile

    __shared__ __align__(16) short vlds[2][8192];   // 2 x 16KB (64 keys x 128c)

    s16x8 bqA = *(const s16x8*)(qb + ((size_t)(b * NNPOS) + q0      + c31) * 16 + h * 8);
    s16x8 bqB = *(const s16x8*)(qb + ((size_t)(b * NNPOS) + q0 + 32 + c31) * 16 + h * 8);

    f32x16 acc[2][4];
    #pragma unroll
    for (int t = 0; t < 2; ++t)
        #pragma unroll
        for (int ct = 0; ct < 4; ++ct)
            #pragma unroll
            for (int r = 0; r < 16; ++r) acc[t][ct][r] = 0.0f;
    float lpA0 = 0.f, lpA1 = 0.f, lpB0 = 0.f, lpB1 = 0.f;

    const short* kbp = kb + (size_t)(b * NNPOS) * 16;
    const int mbase  = s * (NNPOS / KSP);               // 512 keys/split
    const short* vtile = vt + (size_t)b * (NC * NNPOS) + ((size_t)(mbase >> 4) << 11);

    f32x16 z;
    #pragma unroll
    for (int r = 0; r < 16; ++r) z[r] = 0.0f;

    // prologue: stage iter 0 into buf 0; prefetch K for iter 0
    #pragma unroll
    for (int j = 0; j < 4; ++j)
        gload_lds16(vtile + (tid << 3) + (j << 11),
                    &vlds[0][0] + (tid << 3) + (j << 11));
    int m0 = mbase;
    s16x8 ak0 = *(const s16x8*)(kbp + (size_t)(m0      + c31) * 16 + h * 8);
    s16x8 ak1 = *(const s16x8*)(kbp + (size_t)(m0 + 32 + c31) * 16 + h * 8);
    __syncthreads();

    int buf = 0;
    #pragma unroll 1
    for (int it = 0; it < NNPOS / KSP / 64; ++it) {      // 8 iters
        // issue next-tile V staging into the other buffer
        if (it + 1 < NNPOS / KSP / 64) {
            const short* src = vtile + (((size_t)(it + 1)) << 13);
            short* dst = &vlds[buf ^ 1][0];
            #pragma unroll
            for (int j = 0; j < 4; ++j)
                gload_lds16(src + (tid << 3) + (j << 11),
                            dst + (tid << 3) + (j << 11));
        }

        // ---- tile A scores -> exp/pack (keeps only one score pair live)
        s16x8 paA[4], paB[4];
        {
            f32x16 s0 = __builtin_amdgcn_mfma_f32_32x32x16_bf16(ak0, bqA, z, 0, 0, 0);
            f32x16 s1 = __builtin_amdgcn_mfma_f32_32x32x16_bf16(ak1, bqA, z, 0, 0, 0);
            #pragma unroll
            for (int p = 0; p < 4; ++p) {
                const f32x16& sv = (p < 2) ? s0 : s1;
                const int off = (p & 1) * 8;
                union { int i[4]; s16x8 v; } u;
                #pragma unroll
                for (int j = 0; j < 4; ++j) {
                    float p0 = exp2fast(sv[off + 2 * j]);
                    float p1 = exp2fast(sv[off + 2 * j + 1]);
                    if (j & 1) lpA1 += p0 + p1; else lpA0 += p0 + p1;
                    u.i[j] = packbf2(p0, p1);
                }
                paA[p] = u.v;
            }
        }
        // ---- tile B scores -> exp/pack
        {
            f32x16 s0 = __builtin_amdgcn_mfma_f32_32x32x16_bf16(ak0, bqB, z, 0, 0, 0);
            f32x16 s1 = __builtin_amdgcn_mfma_f32_32x32x16_bf16(ak1, bqB, z, 0, 0, 0);
            #pragma unroll
            for (int p = 0; p < 4; ++p) {
                const f32x16& sv = (p < 2) ? s0 : s1;
                const int off = (p & 1) * 8;
                union { int i[4]; s16x8 v; } u;
                #pragma unroll
                for (int j = 0; j < 4; ++j) {
                    float p0 = exp2fast(sv[off + 2 * j]);
                    float p1 = exp2fast(sv[off + 2 * j + 1]);
                    if (j & 1) lpB1 += p0 + p1; else lpB0 += p0 + p1;
                    u.i[j] = packbf2(p0, p1);
                }
                paB[p] = u.v;
            }
        }

        // prefetch next iter's K (ak0/ak1 dead after the score MFMAs)
        if (it + 1 < NNPOS / KSP / 64) {
            m0 += 64;
            ak0 = *(const s16x8*)(kbp + (size_t)(m0      + c31) * 16 + h * 8);
            ak1 = *(const s16x8*)(kbp + (size_t)(m0 + 32 + c31) * 16 + h * 8);
        }

        // PV: one ds_read_b128 per (p,ct) feeds BOTH q-tiles' MFMAs
        const short* vb = &vlds[buf][0];
        #pragma unroll
        for (int p = 0; p < 4; ++p)
            #pragma unroll
            for (int ct = 0; ct < 4; ++ct) {
                s16x8 vf = *(const s16x8*)&vb[((p * 4 + ct) << 9) + (lane << 3)];
                acc[0][ct] = __builtin_amdgcn_mfma_f32_32x32x16_bf16(
                    paA[p], vf, acc[0][ct], 0, 0, 0);
                acc[1][ct] = __builtin_amdgcn_mfma_f32_32x32x16_bf16(
                    paB[p], vf, acc[1][ct], 0, 0, 0);
            }

        __syncthreads();   // staging of it+1 complete; reads of buf done
        buf ^= 1;
    }

    float lpA = lpA0 + lpA1;
    float lpB = lpB0 + lpB1;
    lpA += __shfl_xor(lpA, 32, 64);
    lpB += __shfl_xor(lpB, 32, 64);
    if (lane < 32) {
        lw[((size_t)(b * KSP + s)) * NNPOS + q0      + c31] = lpA;
        lw[((size_t)(b * KSP + s)) * NNPOS + q0 + 32 + c31] = lpB;
    }

    // O partial: [b][s][n][c] bf16 (both q-tiles)
    #pragma unroll
    for (int ct = 0; ct < 4; ++ct)
        #pragma unroll
        for (int r = 0; r < 16; ++r) {
            int q = q0 + (r & 3) + 8 * (r >> 2) + 4 * h;
            Ow[(((size_t)(b * KSP + s)) * NNPOS + q) * NC + ct * 32 + c31] =
                (unsigned short)bf16s(acc[0][ct][r]);
            Ow[(((size_t)(b * KSP + s)) * NNPOS + q + 32) * NC + ct * 32 + c31] =
                (unsigned short)bf16s(acc[1][ct][r]);
        }
}

// ------------------------------------------------------------------
// Kernel 3: combine split-K partials + epilogue.
// out[b][c][n] = gamma * (sum_s O[b][s][n][c]) / (sum_s l[b][s][n]) + x
// ------------------------------------------------------------------
__global__ __launch_bounds__(256) void combine_kernel(
    const unsigned short* __restrict__ Ow, const float* __restrict__ lw,
    const float* __restrict__ x, const float* __restrict__ gamma,
    float* __restrict__ out)
{
    const int n0  = blockIdx.x * 64;
    const int b   = blockIdx.y;
    const int tid = threadIdx.x;

    __shared__ float ot[128 * 65 + 64];
    float* lsum = ot + 128 * 65;

    if (tid < 64) {
        float sl = 0.f;
        #pragma unroll
        for (int sI = 0; sI < KSP; ++sI)
            sl += lw[((size_t)(b * KSP + sI)) * NNPOS + n0 + tid];
        lsum[tid] = 1.0f / sl;
    }
    __syncthreads();

    #pragma unroll
    for (int p = 0; p < 4; ++p) {
        int e = tid + p * 256;          // over 16 c-octs x 64 n
        int co = e & 15, n = e >> 4;
        float a[8] = {0.f, 0.f, 0.f, 0.f, 0.f, 0.f, 0.f, 0.f};
        #pragma unroll
        for (int sI = 0; sI < KSP; ++sI) {
            const unsigned short* src = Ow +
                (((size_t)(b * KSP + sI)) * NNPOS + n0 + n) * NC + co * 8;
            union { s16x8 v; unsigned short us[8]; } u;
            u.v = *(const s16x8*)src;
            #pragma unroll
            for (int j = 0; j < 8; ++j) a[j] += bf2f(u.us[j]);
        }
        float inv = lsum[n];
        #pragma unroll
        for (int j = 0; j < 8; ++j)
            ot[(co * 8 + j) * 65 + n] = a[j] * inv;
    }
    __syncthreads();

    const float g = gamma[0];
    #pragma unroll
    for (int p = 0; p < 8; ++p) {
        int e = tid + p * 256;          // over 128 c x 16 n-quads
        int nq = e & 15, c = e >> 4;
        size_t a = ((size_t)(b * NC + c)) * NNPOS + n0 + nq * 4;
        float4 xv = *(const float4*)&x[a];
        float4 o;
        o.x = g * ot[c * 65 + nq * 4]     + xv.x;
        o.y = g * ot[c * 65 + nq * 4 + 1] + xv.y;
        o.z = g * ot[c * 65 + nq * 4 + 2] + xv.z;
        o.w = g * ot[c * 65 + nq * 4 + 3] + xv.w;
        *(float4*)&out[a] = o;
    }
}

// ------------------------------------------------------------------
extern "C" void kernel_launch(void* const* d_in, const int* in_sizes, int n_in,
                              void* d_out, int out_size, void* d_ws, size_t ws_size,
                              hipStream_t stream) {
    const float* x     = (const float*)d_in[0];
    const float* wq    = (const float*)d_in[1];
    const float* bq    = (const float*)d_in[2];
    const float* wk    = (const float*)d_in[3];
    const float* bk    = (const float*)d_in[4];
    const float* wv    = (const float*)d_in[5];
    const float* bv    = (const float*)d_in[6];
    const float* gamma = (const float*)d_in[7];
    float* out = (float*)d_out;

    // ws: qb 512KB | kb 512KB | vt 4MB | Ow 33.5MB | lw 512KB
    short* qb = (short*)d_ws;
    short* kb = qb + (size_t)NB * NNPOS * 16;
    short* vt = kb + (size_t)NB * NNPOS * 16;
    unsigned short* Ow = (unsigned short*)(vt + (size_t)NB * NC * NNPOS);
    float* lw = (float*)(Ow + (size_t)NB * KSP * NNPOS * NC);

    qkv_kernel<<<dim3(128, NB), 256, 0, stream>>>(x, wq, bq, wk, bk, wv, bv, qb, kb, vt);
    attn_kernel<<<dim3(KSP, 16, NB), 256, 0, stream>>>(qb, kb, vt, Ow, lw);
    combine_kernel<<<dim3(NNPOS / 64, NB), 256, 0, stream>>>(Ow, lw, x, gamma, out);
}